// Round 1
// 156.901 us; speedup vs baseline: 1.0874x; 1.0874x over previous
//
#include <hip/hip_runtime.h>
#include <hip/hip_bf16.h>

#define B_   8
#define N_   10000
#define H_   128
#define DIN_ 256
#define E_   160000

typedef unsigned int uint_;
typedef unsigned short ushort_;
typedef __attribute__((ext_vector_type(8))) short short8;
typedef __attribute__((ext_vector_type(4))) float f32x4;

__device__ __forceinline__ float sigmoidf_(float v) { return 1.f / (1.f + __expf(-v)); }
// tanh via exp, safe at +/-inf
__device__ __forceinline__ float tanh_fast(float v) { float e = __expf(2.f * v); return 1.f - 2.f / (e + 1.f); }

__device__ __forceinline__ ushort_ f2bf(float f) {
    union { float f; uint_ u; } v; v.f = f;
    uint_ r = v.u + 0x7fff + ((v.u >> 16) & 1);   // round-to-nearest-even
    return (ushort_)(r >> 16);
}
#define BF_LO(u) __uint_as_float((u) << 16)
#define BF_HI(u) __uint_as_float((u) & 0xffff0000u)

// ---- transpose + cast gcn_w (k,n) fp32 -> WT (n,k) bf16 -----------------
__global__ __launch_bounds__(256) void wt_k(const float* __restrict__ w, ushort_* __restrict__ wt) {
    const int t = threadIdx.x;
    const int n = t >> 1;
    const int kb = (t & 1) * 64;
    #pragma unroll
    for (int i = 0; i < 8; ++i) {
        int k = kb + i * 8;
        uint4 o;
        o.x = (uint_)f2bf(w[(k + 0) * H_ + n]) | ((uint_)f2bf(w[(k + 1) * H_ + n]) << 16);
        o.y = (uint_)f2bf(w[(k + 2) * H_ + n]) | ((uint_)f2bf(w[(k + 3) * H_ + n]) << 16);
        o.z = (uint_)f2bf(w[(k + 4) * H_ + n]) | ((uint_)f2bf(w[(k + 5) * H_ + n]) << 16);
        o.w = (uint_)f2bf(w[(k + 6) * H_ + n]) | ((uint_)f2bf(w[(k + 7) * H_ + n]) << 16);
        *(uint4*)(wt + n * H_ + k) = o;
    }
}

// ---- degrees ------------------------------------------------------------
__global__ __launch_bounds__(256) void degrees_k(const int* __restrict__ src, const int* __restrict__ dst,
                                                 int* __restrict__ out_deg, int* __restrict__ in_deg) {
    int e = blockIdx.x * 256 + threadIdx.x;
    if (e < E_) {
        atomicAdd(&out_deg[src[e]], 1);
        atomicAdd(&in_deg[dst[e]], 1);
    }
}

// ---- norms + exclusive scan of in_deg -> CSR row offsets ----------------
__global__ __launch_bounds__(1024) void norms_scan_k(const int* __restrict__ out_deg, const int* __restrict__ in_deg,
                                                     float* __restrict__ norm_out, float* __restrict__ norm_in,
                                                     int* __restrict__ offsets) {
    __shared__ int part[1024];
    const int tid = threadIdx.x;
    const int CH = 10;               // 1024*10 >= 10000
    int base = tid * CH;
    int local[CH];
    int s = 0;
    #pragma unroll
    for (int q = 0; q < CH; ++q) {
        int n = base + q;
        int d = (n < N_) ? in_deg[n] : 0;
        local[q] = s;
        s += d;
        if (n < N_) {
            int od = out_deg[n];
            norm_out[n] = od > 0 ? rsqrtf((float)od) : 0.f;
            norm_in[n]  = d  > 0 ? rsqrtf((float)d)  : 0.f;
        }
    }
    part[tid] = s;
    __syncthreads();
    for (int off = 1; off < 1024; off <<= 1) {
        int v = (tid >= off) ? part[tid - off] : 0;
        __syncthreads();
        part[tid] += v;
        __syncthreads();
    }
    int pre = (tid > 0) ? part[tid - 1] : 0;
    #pragma unroll
    for (int q = 0; q < CH; ++q) {
        int n = base + q;
        if (n < N_) offsets[n] = pre + local[q];
    }
    if (tid == 1023) offsets[N_] = part[1023];
}

// ---- bucket-fill CSR (order within bucket arbitrary; fp tolerance ok) ---
__global__ __launch_bounds__(256) void fill_csr_k(const int* __restrict__ src, const int* __restrict__ dst,
                                                  const int* __restrict__ offsets, int* __restrict__ cursor,
                                                  const float* __restrict__ norm_out,
                                                  int* __restrict__ csr_src, float* __restrict__ csr_coef) {
    int e = blockIdx.x * 256 + threadIdx.x;
    if (e < E_) {
        int d = dst[e];
        int s = src[e];
        int pos = offsets[d] + atomicAdd(&cursor[d], 1);
        csr_src[pos]  = s;
        csr_coef[pos] = norm_out[s];
    }
}

// ---- x projections: grid (3 gates, 8 batches), 2-way D split + LDS reduce
__global__ __launch_bounds__(256) void xproj_k(const float* __restrict__ x,
                                               const float* __restrict__ w_r, const float* __restrict__ b_r,
                                               const float* __restrict__ w_z, const float* __restrict__ b_z,
                                               const float* __restrict__ w_h, const float* __restrict__ b_h,
                                               float* __restrict__ xr, float* __restrict__ xz, float* __restrict__ xh) {
    const int g = blockIdx.x, b = blockIdx.y;
    const float* __restrict__ w  = g == 0 ? w_r : (g == 1 ? w_z : w_h);
    const float* __restrict__ bs = g == 0 ? b_r : (g == 1 ? b_z : b_h);
    float* __restrict__ o        = g == 0 ? xr  : (g == 1 ? xz  : xh);
    const int k = threadIdx.x & 127, half = threadIdx.x >> 7;
    const float* xb = x + b * DIN_;
    float a = 0.f;
    #pragma unroll 8
    for (int d = half * 128; d < half * 128 + 128; ++d)
        a += xb[d] * w[d * H_ + k];
    __shared__ float part[2][128];
    part[half][k] = a;
    __syncthreads();
    if (half == 0) o[b * H_ + k] = a + part[1][k] + bs[k];
}

// ---- GEMM-first: hw = bf16(h_prev @ gcn_w), flattened (B*N, H) ----------
// GraphConv is linear: norm_in*(A(norm_out*h))@W == norm_in*(A(norm_out*(h@W))).
// This replaces BOTH cast_k and the old post-agg gemm_gru_k's GEMM, and
// removes the 41MB agg intermediate round-trip.
// Block: 64 rows x 128 cols; 4 waves x 16 rows. Same swizzled-LDS scheme.
__global__ __launch_bounds__(256) void gemm_cast_k(const float* __restrict__ h,
                                                   const ushort_* __restrict__ wt,
                                                   ushort_* __restrict__ hw) {
    __shared__ ushort_ WT_s[H_ * H_];   // [n][k] bf16, swizzled: 32 KB
    __shared__ ushort_ A_s[64 * H_];    // [row][k] bf16, swizzled: 16 KB
    const int tid = threadIdx.x;
    const size_t rbase = (size_t)blockIdx.x * 64;   // B_*N_ = 80000 = 1250*64 exact

    // stage W^T: 2048 16B-chunks; swizzle k-ushorts by ((n&7)<<3)
    #pragma unroll
    for (int i = 0; i < 8; ++i) {
        int c = i * 256 + tid;
        int n = c >> 4;
        int kus = (c & 15) * 8;
        uint4 v = ((const uint4*)wt)[c];
        *(uint4*)&WT_s[n * H_ + (kus ^ ((n & 7) << 3))] = v;
    }
    // stage A tile: 64x128 fp32 rows of h_prev -> bf16, swizzled
    #pragma unroll
    for (int i = 0; i < 8; ++i) {
        int f4 = i * 256 + tid;           // float4 id within tile (0..2047)
        int row = f4 >> 5;
        int col4 = (f4 & 31) * 4;
        f32x4 v = *(const f32x4*)&h[(rbase + row) * H_ + col4];
        uint2 p;
        p.x = (uint_)f2bf(v[0]) | ((uint_)f2bf(v[1]) << 16);
        p.y = (uint_)f2bf(v[2]) | ((uint_)f2bf(v[3]) << 16);
        *(uint2*)&A_s[row * H_ + (col4 ^ ((row & 7) << 3))] = p;
    }
    __syncthreads();

    const int l = tid & 63;
    const int w = tid >> 6;
    const int lr = l & 15;
    const int kg = (l >> 4) * 8;
    const int arow = w * 16 + lr;

    f32x4 acc[8];
    #pragma unroll
    for (int nf = 0; nf < 8; ++nf) acc[nf] = (f32x4){0.f, 0.f, 0.f, 0.f};

    #pragma unroll
    for (int kk = 0; kk < 4; ++kk) {
        int kus = kk * 32 + kg;
        short8 av = *(const short8*)&A_s[arow * H_ + (kus ^ ((arow & 7) << 3))];
        #pragma unroll
        for (int nf = 0; nf < 8; ++nf) {
            int nrow = nf * 16 + lr;
            short8 bv = *(const short8*)&WT_s[nrow * H_ + (kus ^ ((nrow & 7) << 3))];
            acc[nf] = __builtin_amdgcn_mfma_f32_16x16x32_bf16(av, bv, acc[nf], 0, 0, 0);
        }
    }

    // epilogue: C/D layout col = lane&15, row = (lane>>4)*4 + r (m89).
    // Scatter acc into this wave's own A_s rows as bf16 (swizzled), then
    // read back row-contiguous for coalesced 64B/lane global stores.
    const int wrow0 = w * 16 + (l >> 4) * 4;
    #pragma unroll
    for (int nf = 0; nf < 8; ++nf) {
        int col = nf * 16 + lr;
        #pragma unroll
        for (int r = 0; r < 4; ++r) {
            int row = wrow0 + r;
            A_s[row * H_ + (col ^ ((row & 7) << 3))] = f2bf(acc[nf][r]);
        }
    }
    __syncthreads();   // cross-lane LDS transpose: make visibility explicit
    {
        int row = w * 16 + (l >> 2);      // 16 rows x 4 col-groups per wave
        int c0 = (l & 3) * 32;            // 32 ushorts = 64B per lane
        int swz = (row & 7) << 3;
        uint4 o0 = *(const uint4*)&A_s[row * H_ + ((c0 +  0) ^ swz)];
        uint4 o1 = *(const uint4*)&A_s[row * H_ + ((c0 +  8) ^ swz)];
        uint4 o2 = *(const uint4*)&A_s[row * H_ + ((c0 + 16) ^ swz)];
        uint4 o3 = *(const uint4*)&A_s[row * H_ + ((c0 + 24) ^ swz)];
        uint4* dst = (uint4*)(hw + (rbase + row) * H_ + c0);
        dst[0] = o0; dst[1] = o1; dst[2] = o2; dst[3] = o3;
    }
}

#define FMA8(A, c, u)                                       \
    A[0] += (c) * BF_LO((u).x); A[1] += (c) * BF_HI((u).x); \
    A[2] += (c) * BF_LO((u).y); A[3] += (c) * BF_HI((u).y); \
    A[4] += (c) * BF_LO((u).z); A[5] += (c) * BF_HI((u).z); \
    A[6] += (c) * BF_LO((u).w); A[7] += (c) * BF_HI((u).w);

// ---- aggregation of hw + fused GRU: one WAVE per dst node, 8 batches ----
// acc = sum_e coef * hw[src]; h_conv = acc*norm_in + gcn_b; then GRU.
__global__ __launch_bounds__(256) void agg_gru_k(const ushort_* __restrict__ hw, const int* __restrict__ offsets,
                                                 const float* __restrict__ norm_in,
                                                 const int* __restrict__ csr_src, const float* __restrict__ csr_coef,
                                                 const float* __restrict__ gcn_b,
                                                 const float* __restrict__ xr, const float* __restrict__ xz,
                                                 const float* __restrict__ xh,
                                                 const float* __restrict__ h_prev, float* __restrict__ out) {
    const int lane = threadIdx.x & 63;
    const int wave = threadIdx.x >> 6;
    const int n = blockIdx.x * 4 + wave;              // grid.x = N/4 exact
    const int b = lane >> 3;
    const int h0 = (lane & 7) * 16;
    const ushort_* __restrict__ hb = hw + (size_t)b * (N_ * H_) + h0;
    int o  = offsets[n];
    int dc = offsets[n + 1] - o;
    float acc[16];
    #pragma unroll
    for (int k = 0; k < 16; ++k) acc[k] = 0.f;
    int j = 0;
    for (; j + 2 <= dc; j += 2) {
        int   s0 = csr_src[o + j],  s1 = csr_src[o + j + 1];
        float c0 = csr_coef[o + j], c1 = csr_coef[o + j + 1];
        uint4 u0 = *(const uint4*)(hb + (size_t)s0 * H_);
        uint4 u1 = *(const uint4*)(hb + (size_t)s0 * H_ + 8);
        uint4 v0 = *(const uint4*)(hb + (size_t)s1 * H_);
        uint4 v1 = *(const uint4*)(hb + (size_t)s1 * H_ + 8);
        FMA8(acc, c0, u0); FMA8((acc + 8), c0, u1);
        FMA8(acc, c1, v0); FMA8((acc + 8), c1, v1);
    }
    if (j < dc) {
        int   s = csr_src[o + j];
        float c = csr_coef[o + j];
        uint4 u0 = *(const uint4*)(hb + (size_t)s * H_);
        uint4 u1 = *(const uint4*)(hb + (size_t)s * H_ + 8);
        FMA8(acc, c, u0); FMA8((acc + 8), c, u1);
    }
    float ni = norm_in[n];
    size_t off = ((size_t)b * N_ + n) * H_ + h0;
    const float* __restrict__ xrb = xr + b * H_ + h0;
    const float* __restrict__ xzb = xz + b * H_ + h0;
    const float* __restrict__ xhb = xh + b * H_ + h0;
    const float* __restrict__ gbb = gcn_b + h0;
    #pragma unroll
    for (int q = 0; q < 4; ++q) {
        f32x4 hp = *(const f32x4*)(h_prev + off + q * 4);
        f32x4 gb = *(const f32x4*)(gbb + q * 4);
        f32x4 vr = *(const f32x4*)(xrb + q * 4);
        f32x4 vz = *(const f32x4*)(xzb + q * 4);
        f32x4 vh = *(const f32x4*)(xhb + q * 4);
        f32x4 wv;
        #pragma unroll
        for (int t = 0; t < 4; ++t) {
            float hc = acc[q * 4 + t] * ni + gb[t];
            float rr = sigmoidf_(vr[t] + hc);
            float zz = sigmoidf_(vz[t] + hc);
            float ht = tanh_fast(vh[t] + rr * hc);
            wv[t] = (1.f - zz) * hp[t] + zz * ht;
        }
        *(f32x4*)(out + off + q * 4) = wv;
    }
}

extern "C" void kernel_launch(void* const* d_in, const int* in_sizes, int n_in,
                              void* d_out, int out_size, void* d_ws, size_t ws_size,
                              hipStream_t stream) {
    (void)in_sizes; (void)n_in; (void)out_size; (void)ws_size;
    const float* x      = (const float*)d_in[0];
    const float* h_prev = (const float*)d_in[1];
    const int*   src    = (const int*)d_in[2];
    const int*   dst    = (const int*)d_in[3];
    const float* w_r    = (const float*)d_in[4];
    const float* b_r    = (const float*)d_in[5];
    const float* w_z    = (const float*)d_in[6];
    const float* b_z    = (const float*)d_in[7];
    const float* w_h    = (const float*)d_in[8];
    const float* b_h    = (const float*)d_in[9];
    const float* gcn_w  = (const float*)d_in[10];
    const float* gcn_b  = (const float*)d_in[11];
    float* out = (float*)d_out;

    ushort_* hw = (ushort_*)d_ws;                        // B*N*H bf16 = 20.48 MB
    int* wsi = (int*)(hw + (size_t)B_ * N_ * H_);
    int* out_deg   = wsi;                       // N
    int* in_deg    = wsi + N_;                  // N
    int* cursor    = wsi + 2 * N_;              // N
    int* offsets   = wsi + 3 * N_;              // N+1
    float* norm_out = (float*)(wsi + 4 * N_ + 1);  // N
    float* norm_in  = norm_out + N_;               // N
    int*   csr_src  = (int*)(norm_in + N_);        // E
    float* csr_coef = (float*)(csr_src + E_);      // E
    float* xr = csr_coef + E_;                     // B*H
    float* xz = xr + B_ * H_;
    float* xh = xz + B_ * H_;
    ushort_* wt = (ushort_*)(xh + B_ * H_);        // H*H bf16 = 32 KB

    hipMemsetAsync(out_deg, 0, 3 * N_ * sizeof(int), stream);  // out_deg, in_deg, cursor
    wt_k<<<1, 256, 0, stream>>>(gcn_w, wt);
    degrees_k<<<(E_ + 255) / 256, 256, 0, stream>>>(src, dst, out_deg, in_deg);
    norms_scan_k<<<1, 1024, 0, stream>>>(out_deg, in_deg, norm_out, norm_in, offsets);
    fill_csr_k<<<(E_ + 255) / 256, 256, 0, stream>>>(src, dst, offsets, cursor, norm_out, csr_src, csr_coef);
    xproj_k<<<dim3(3, B_), 256, 0, stream>>>(x, w_r, b_r, w_z, b_z, w_h, b_h, xr, xz, xh);
    gemm_cast_k<<<(B_ * N_) / 64, 256, 0, stream>>>(h_prev, wt, hw);
    agg_gru_k<<<N_ / 4, 256, 0, stream>>>(hw, offsets, norm_in, csr_src, csr_coef,
                                          gcn_b, xr, xz, xh, h_prev, out);
}

// Round 2
// 147.136 us; speedup vs baseline: 1.1596x; 1.0664x over previous
//
#include <hip/hip_runtime.h>
#include <hip/hip_bf16.h>

#define B_   8
#define N_   10000
#define H_   128
#define DIN_ 256
#define E_   160000

typedef unsigned int uint_;
typedef unsigned short ushort_;
typedef __attribute__((ext_vector_type(8))) short short8;
typedef __attribute__((ext_vector_type(4))) float f32x4;

__device__ __forceinline__ float sigmoidf_(float v) { return 1.f / (1.f + __expf(-v)); }
// tanh via exp, safe at +/-inf
__device__ __forceinline__ float tanh_fast(float v) { float e = __expf(2.f * v); return 1.f - 2.f / (e + 1.f); }

__device__ __forceinline__ ushort_ f2bf(float f) {
    union { float f; uint_ u; } v; v.f = f;
    uint_ r = v.u + 0x7fff + ((v.u >> 16) & 1);   // round-to-nearest-even
    return (ushort_)(r >> 16);
}
#define BF_LO(u) __uint_as_float((u) << 16)
#define BF_HI(u) __uint_as_float((u) & 0xffff0000u)

// ---- degrees ------------------------------------------------------------
__global__ __launch_bounds__(256) void degrees_k(const int* __restrict__ src, const int* __restrict__ dst,
                                                 int* __restrict__ out_deg, int* __restrict__ in_deg) {
    int e = blockIdx.x * 256 + threadIdx.x;
    if (e < E_) {
        atomicAdd(&out_deg[src[e]], 1);
        atomicAdd(&in_deg[dst[e]], 1);
    }
}

// ---- norms + exclusive scan of in_deg -> CSR row offsets ----------------
__global__ __launch_bounds__(1024) void norms_scan_k(const int* __restrict__ out_deg, const int* __restrict__ in_deg,
                                                     float* __restrict__ norm_out, float* __restrict__ norm_in,
                                                     int* __restrict__ offsets) {
    __shared__ int part[1024];
    const int tid = threadIdx.x;
    const int CH = 10;               // 1024*10 >= 10000
    int base = tid * CH;
    int local[CH];
    int s = 0;
    #pragma unroll
    for (int q = 0; q < CH; ++q) {
        int n = base + q;
        int d = (n < N_) ? in_deg[n] : 0;
        local[q] = s;
        s += d;
        if (n < N_) {
            int od = out_deg[n];
            norm_out[n] = od > 0 ? rsqrtf((float)od) : 0.f;
            norm_in[n]  = d  > 0 ? rsqrtf((float)d)  : 0.f;
        }
    }
    part[tid] = s;
    __syncthreads();
    for (int off = 1; off < 1024; off <<= 1) {
        int v = (tid >= off) ? part[tid - off] : 0;
        __syncthreads();
        part[tid] += v;
        __syncthreads();
    }
    int pre = (tid > 0) ? part[tid - 1] : 0;
    #pragma unroll
    for (int q = 0; q < CH; ++q) {
        int n = base + q;
        if (n < N_) offsets[n] = pre + local[q];
    }
    if (tid == 1023) offsets[N_] = part[1023];
}

// ---- bucket-fill CSR (order within bucket arbitrary; fp tolerance ok) ---
__global__ __launch_bounds__(256) void fill_csr_k(const int* __restrict__ src, const int* __restrict__ dst,
                                                  const int* __restrict__ offsets, int* __restrict__ cursor,
                                                  const float* __restrict__ norm_out,
                                                  int* __restrict__ csr_src, float* __restrict__ csr_coef) {
    int e = blockIdx.x * 256 + threadIdx.x;
    if (e < E_) {
        int d = dst[e];
        int s = src[e];
        int pos = offsets[d] + atomicAdd(&cursor[d], 1);
        csr_src[pos]  = s;
        csr_coef[pos] = norm_out[s];
    }
}

// ---- x projections + W^T cast: grid (4, 8); g==3 does wt transpose ------
__global__ __launch_bounds__(256) void xproj_k(const float* __restrict__ x,
                                               const float* __restrict__ w_r, const float* __restrict__ b_r,
                                               const float* __restrict__ w_z, const float* __restrict__ b_z,
                                               const float* __restrict__ w_h, const float* __restrict__ b_h,
                                               const float* __restrict__ gcn_w, ushort_* __restrict__ wt,
                                               float* __restrict__ xr, float* __restrict__ xz, float* __restrict__ xh) {
    const int g = blockIdx.x, b = blockIdx.y;
    if (g == 3) {                    // transpose + cast gcn_w (k,n) -> WT (n,k) bf16
        if (b != 0) return;
        const int t = threadIdx.x;
        const int n = t >> 1;
        const int kb = (t & 1) * 64;
        #pragma unroll
        for (int i = 0; i < 8; ++i) {
            int k = kb + i * 8;
            uint4 o;
            o.x = (uint_)f2bf(gcn_w[(k + 0) * H_ + n]) | ((uint_)f2bf(gcn_w[(k + 1) * H_ + n]) << 16);
            o.y = (uint_)f2bf(gcn_w[(k + 2) * H_ + n]) | ((uint_)f2bf(gcn_w[(k + 3) * H_ + n]) << 16);
            o.z = (uint_)f2bf(gcn_w[(k + 4) * H_ + n]) | ((uint_)f2bf(gcn_w[(k + 5) * H_ + n]) << 16);
            o.w = (uint_)f2bf(gcn_w[(k + 6) * H_ + n]) | ((uint_)f2bf(gcn_w[(k + 7) * H_ + n]) << 16);
            *(uint4*)(wt + n * H_ + k) = o;
        }
        return;
    }
    const float* __restrict__ w  = g == 0 ? w_r : (g == 1 ? w_z : w_h);
    const float* __restrict__ bs = g == 0 ? b_r : (g == 1 ? b_z : b_h);
    float* __restrict__ o        = g == 0 ? xr  : (g == 1 ? xz  : xh);
    const int k = threadIdx.x & 127, half = threadIdx.x >> 7;
    const float* xb = x + b * DIN_;
    float a = 0.f;
    #pragma unroll 8
    for (int d = half * 128; d < half * 128 + 128; ++d)
        a += xb[d] * w[d * H_ + k];
    __shared__ float part[2][128];
    part[half][k] = a;
    __syncthreads();
    if (half == 0) o[b * H_ + k] = a + part[1][k] + bs[k];
}

// ---- GEMM-first: hw = bf16(h_prev @ gcn_w), flattened (B*N, H) ----------
// GraphConv is linear: norm_in*(A(norm_out*h))@W == norm_in*(A(norm_out*(h@W))).
// Block: 64 rows x 128 cols; 4 waves x 16 rows. Swizzled-LDS MFMA scheme.
__global__ __launch_bounds__(256) void gemm_cast_k(const float* __restrict__ h,
                                                   const ushort_* __restrict__ wt,
                                                   ushort_* __restrict__ hw) {
    __shared__ ushort_ WT_s[H_ * H_];   // [n][k] bf16, swizzled: 32 KB
    __shared__ ushort_ A_s[64 * H_];    // [row][k] bf16, swizzled: 16 KB
    const int tid = threadIdx.x;
    const size_t rbase = (size_t)blockIdx.x * 64;   // B_*N_ = 80000 = 1250*64 exact

    // stage W^T: 2048 16B-chunks; swizzle k-ushorts by ((n&7)<<3)
    #pragma unroll
    for (int i = 0; i < 8; ++i) {
        int c = i * 256 + tid;
        int n = c >> 4;
        int kus = (c & 15) * 8;
        uint4 v = ((const uint4*)wt)[c];
        *(uint4*)&WT_s[n * H_ + (kus ^ ((n & 7) << 3))] = v;
    }
    // stage A tile: 64x128 fp32 rows of h_prev -> bf16, swizzled
    #pragma unroll
    for (int i = 0; i < 8; ++i) {
        int f4 = i * 256 + tid;           // float4 id within tile (0..2047)
        int row = f4 >> 5;
        int col4 = (f4 & 31) * 4;
        f32x4 v = *(const f32x4*)&h[(rbase + row) * H_ + col4];
        uint2 p;
        p.x = (uint_)f2bf(v[0]) | ((uint_)f2bf(v[1]) << 16);
        p.y = (uint_)f2bf(v[2]) | ((uint_)f2bf(v[3]) << 16);
        *(uint2*)&A_s[row * H_ + (col4 ^ ((row & 7) << 3))] = p;
    }
    __syncthreads();

    const int l = tid & 63;
    const int w = tid >> 6;
    const int lr = l & 15;
    const int kg = (l >> 4) * 8;
    const int arow = w * 16 + lr;

    f32x4 acc[8];
    #pragma unroll
    for (int nf = 0; nf < 8; ++nf) acc[nf] = (f32x4){0.f, 0.f, 0.f, 0.f};

    #pragma unroll
    for (int kk = 0; kk < 4; ++kk) {
        int kus = kk * 32 + kg;
        short8 av = *(const short8*)&A_s[arow * H_ + (kus ^ ((arow & 7) << 3))];
        #pragma unroll
        for (int nf = 0; nf < 8; ++nf) {
            int nrow = nf * 16 + lr;
            short8 bv = *(const short8*)&WT_s[nrow * H_ + (kus ^ ((nrow & 7) << 3))];
            acc[nf] = __builtin_amdgcn_mfma_f32_16x16x32_bf16(av, bv, acc[nf], 0, 0, 0);
        }
    }

    // epilogue: C/D layout col = lane&15, row = (lane>>4)*4 + r (m89).
    // Scatter acc into this wave's own A_s rows as bf16 (swizzled), then
    // read back row-contiguous for coalesced 64B/lane global stores.
    const int wrow0 = w * 16 + (l >> 4) * 4;
    #pragma unroll
    for (int nf = 0; nf < 8; ++nf) {
        int col = nf * 16 + lr;
        #pragma unroll
        for (int r = 0; r < 4; ++r) {
            int row = wrow0 + r;
            A_s[row * H_ + (col ^ ((row & 7) << 3))] = f2bf(acc[nf][r]);
        }
    }
    __syncthreads();   // cross-lane LDS transpose: make visibility explicit
    {
        int row = w * 16 + (l >> 2);      // 16 rows x 4 col-groups per wave
        int c0 = (l & 3) * 32;            // 32 ushorts = 64B per lane
        int swz = (row & 7) << 3;
        uint4 o0 = *(const uint4*)&A_s[row * H_ + ((c0 +  0) ^ swz)];
        uint4 o1 = *(const uint4*)&A_s[row * H_ + ((c0 +  8) ^ swz)];
        uint4 o2 = *(const uint4*)&A_s[row * H_ + ((c0 + 16) ^ swz)];
        uint4 o3 = *(const uint4*)&A_s[row * H_ + ((c0 + 24) ^ swz)];
        uint4* dst = (uint4*)(hw + (rbase + row) * H_ + c0);
        dst[0] = o0; dst[1] = o1; dst[2] = o2; dst[3] = o3;
    }
}

// ---- aggregation of hw + fused GRU, one batch per XCD -------------------
// Wave = one (node, batch). batch = blockIdx.x & 7: with round-robin
// block->XCD dispatch, all blocks of batch b land on XCD b, so the gather
// working set per XCD is one 2.56 MB hw slice -> resident in 4 MB L2.
// Per edge: 64 lanes x 4B = one coalesced 256B row read.
__global__ __launch_bounds__(256) void agg_gru_k(const ushort_* __restrict__ hw, const int* __restrict__ offsets,
                                                 const float* __restrict__ norm_in,
                                                 const int* __restrict__ csr_src, const float* __restrict__ csr_coef,
                                                 const float* __restrict__ gcn_b,
                                                 const float* __restrict__ xr, const float* __restrict__ xz,
                                                 const float* __restrict__ xh,
                                                 const float* __restrict__ h_prev, float* __restrict__ out) {
    const int lane = threadIdx.x & 63;
    const int wave = threadIdx.x >> 6;
    const int b  = blockIdx.x & 7;                  // XCD-pinned batch
    const int ng = blockIdx.x >> 3;                 // node group (0..2499)
    const int n  = ng * 4 + wave;
    const int h  = lane * 2;                        // 2 elems per lane
    const ushort_* __restrict__ hb = hw + (size_t)b * (N_ * H_) + h;
    int o  = offsets[n];
    int dc = offsets[n + 1] - o;
    float a0 = 0.f, a1 = 0.f;
    int j = 0;
    for (; j + 4 <= dc; j += 4) {
        int   s0 = csr_src[o + j],      s1 = csr_src[o + j + 1];
        int   s2 = csr_src[o + j + 2],  s3 = csr_src[o + j + 3];
        float c0 = csr_coef[o + j],     c1 = csr_coef[o + j + 1];
        float c2 = csr_coef[o + j + 2], c3 = csr_coef[o + j + 3];
        uint_ u0 = *(const uint_*)(hb + (size_t)s0 * H_);
        uint_ u1 = *(const uint_*)(hb + (size_t)s1 * H_);
        uint_ u2 = *(const uint_*)(hb + (size_t)s2 * H_);
        uint_ u3 = *(const uint_*)(hb + (size_t)s3 * H_);
        a0 += c0 * BF_LO(u0); a1 += c0 * BF_HI(u0);
        a0 += c1 * BF_LO(u1); a1 += c1 * BF_HI(u1);
        a0 += c2 * BF_LO(u2); a1 += c2 * BF_HI(u2);
        a0 += c3 * BF_LO(u3); a1 += c3 * BF_HI(u3);
    }
    for (; j < dc; ++j) {
        int   s = csr_src[o + j];
        float c = csr_coef[o + j];
        uint_ u = *(const uint_*)(hb + (size_t)s * H_);
        a0 += c * BF_LO(u); a1 += c * BF_HI(u);
    }
    float ni = norm_in[n];
    size_t off = ((size_t)b * N_ + n) * H_ + h;
    float2 hp = *(const float2*)(h_prev + off);
    float2 gb = *(const float2*)(gcn_b + h);
    float2 vr = *(const float2*)(xr + b * H_ + h);
    float2 vz = *(const float2*)(xz + b * H_ + h);
    float2 vh = *(const float2*)(xh + b * H_ + h);
    float2 wv;
    {
        float hc = a0 * ni + gb.x;
        float rr = sigmoidf_(vr.x + hc);
        float zz = sigmoidf_(vz.x + hc);
        float ht = tanh_fast(vh.x + rr * hc);
        wv.x = (1.f - zz) * hp.x + zz * ht;
    }
    {
        float hc = a1 * ni + gb.y;
        float rr = sigmoidf_(vr.y + hc);
        float zz = sigmoidf_(vz.y + hc);
        float ht = tanh_fast(vh.y + rr * hc);
        wv.y = (1.f - zz) * hp.y + zz * ht;
    }
    *(float2*)(out + off) = wv;
}

extern "C" void kernel_launch(void* const* d_in, const int* in_sizes, int n_in,
                              void* d_out, int out_size, void* d_ws, size_t ws_size,
                              hipStream_t stream) {
    (void)in_sizes; (void)n_in; (void)out_size; (void)ws_size;
    const float* x      = (const float*)d_in[0];
    const float* h_prev = (const float*)d_in[1];
    const int*   src    = (const int*)d_in[2];
    const int*   dst    = (const int*)d_in[3];
    const float* w_r    = (const float*)d_in[4];
    const float* b_r    = (const float*)d_in[5];
    const float* w_z    = (const float*)d_in[6];
    const float* b_z    = (const float*)d_in[7];
    const float* w_h    = (const float*)d_in[8];
    const float* b_h    = (const float*)d_in[9];
    const float* gcn_w  = (const float*)d_in[10];
    const float* gcn_b  = (const float*)d_in[11];
    float* out = (float*)d_out;

    ushort_* hw = (ushort_*)d_ws;                        // B*N*H bf16 = 20.48 MB
    int* wsi = (int*)(hw + (size_t)B_ * N_ * H_);
    int* out_deg   = wsi;                       // N
    int* in_deg    = wsi + N_;                  // N
    int* cursor    = wsi + 2 * N_;              // N
    int* offsets   = wsi + 3 * N_;              // N+1
    float* norm_out = (float*)(wsi + 4 * N_ + 1);  // N
    float* norm_in  = norm_out + N_;               // N
    int*   csr_src  = (int*)(norm_in + N_);        // E
    float* csr_coef = (float*)(csr_src + E_);      // E
    float* xr = csr_coef + E_;                     // B*H
    float* xz = xr + B_ * H_;
    float* xh = xz + B_ * H_;
    ushort_* wt = (ushort_*)(xh + B_ * H_);        // H*H bf16 = 32 KB

    hipMemsetAsync(out_deg, 0, 3 * N_ * sizeof(int), stream);  // out_deg, in_deg, cursor
    degrees_k<<<(E_ + 255) / 256, 256, 0, stream>>>(src, dst, out_deg, in_deg);
    norms_scan_k<<<1, 1024, 0, stream>>>(out_deg, in_deg, norm_out, norm_in, offsets);
    fill_csr_k<<<(E_ + 255) / 256, 256, 0, stream>>>(src, dst, offsets, cursor, norm_out, csr_src, csr_coef);
    xproj_k<<<dim3(4, B_), 256, 0, stream>>>(x, w_r, b_r, w_z, b_z, w_h, b_h, gcn_w, wt, xr, xz, xh);
    gemm_cast_k<<<(B_ * N_) / 64, 256, 0, stream>>>(h_prev, wt, hw);
    agg_gru_k<<<(N_ / 4) * 8, 256, 0, stream>>>(hw, offsets, norm_in, csr_src, csr_coef,
                                                gcn_b, xr, xz, xh, h_prev, out);
}

// Round 3
// 137.825 us; speedup vs baseline: 1.2379x; 1.0676x over previous
//
#include <hip/hip_runtime.h>
#include <hip/hip_bf16.h>

#define B_   8
#define N_   10000
#define H_   128
#define DIN_ 256
#define E_   160000

typedef unsigned int uint_;
typedef unsigned short ushort_;
typedef __attribute__((ext_vector_type(8))) short short8;
typedef __attribute__((ext_vector_type(4))) float f32x4;

__device__ __forceinline__ float sigmoidf_(float v) { return 1.f / (1.f + __expf(-v)); }
// tanh via exp, safe at +/-inf
__device__ __forceinline__ float tanh_fast(float v) { float e = __expf(2.f * v); return 1.f - 2.f / (e + 1.f); }

__device__ __forceinline__ ushort_ f2bf(float f) {
    union { float f; uint_ u; } v; v.f = f;
    uint_ r = v.u + 0x7fff + ((v.u >> 16) & 1);   // round-to-nearest-even
    return (ushort_)(r >> 16);
}
#define BF_LO(u) __uint_as_float((u) << 16)
#define BF_HI(u) __uint_as_float((u) & 0xffff0000u)

// ---- degrees ------------------------------------------------------------
__global__ __launch_bounds__(256) void degrees_k(const int* __restrict__ src, const int* __restrict__ dst,
                                                 int* __restrict__ out_deg, int* __restrict__ in_deg) {
    int e = blockIdx.x * 256 + threadIdx.x;
    if (e < E_) {
        atomicAdd(&out_deg[src[e]], 1);
        atomicAdd(&in_deg[dst[e]], 1);
    }
}

// ---- norms + exclusive scan of in_deg -> CSR row offsets ----------------
__global__ __launch_bounds__(1024) void norms_scan_k(const int* __restrict__ out_deg, const int* __restrict__ in_deg,
                                                     float* __restrict__ norm_out, float* __restrict__ norm_in,
                                                     int* __restrict__ offsets) {
    __shared__ int part[1024];
    const int tid = threadIdx.x;
    const int CH = 10;               // 1024*10 >= 10000
    int base = tid * CH;
    int local[CH];
    int s = 0;
    #pragma unroll
    for (int q = 0; q < CH; ++q) {
        int n = base + q;
        int d = (n < N_) ? in_deg[n] : 0;
        local[q] = s;
        s += d;
        if (n < N_) {
            int od = out_deg[n];
            norm_out[n] = od > 0 ? rsqrtf((float)od) : 0.f;
            norm_in[n]  = d  > 0 ? rsqrtf((float)d)  : 0.f;
        }
    }
    part[tid] = s;
    __syncthreads();
    for (int off = 1; off < 1024; off <<= 1) {
        int v = (tid >= off) ? part[tid - off] : 0;
        __syncthreads();
        part[tid] += v;
        __syncthreads();
    }
    int pre = (tid > 0) ? part[tid - 1] : 0;
    #pragma unroll
    for (int q = 0; q < CH; ++q) {
        int n = base + q;
        if (n < N_) offsets[n] = pre + local[q];
    }
    if (tid == 1023) offsets[N_] = part[1023];
}

// ---- bucket-fill CSR (order within bucket arbitrary; fp tolerance ok) ---
__global__ __launch_bounds__(256) void fill_csr_k(const int* __restrict__ src, const int* __restrict__ dst,
                                                  const int* __restrict__ offsets, int* __restrict__ cursor,
                                                  const float* __restrict__ norm_out,
                                                  int* __restrict__ csr_src, float* __restrict__ csr_coef) {
    int e = blockIdx.x * 256 + threadIdx.x;
    if (e < E_) {
        int d = dst[e];
        int s = src[e];
        int pos = offsets[d] + atomicAdd(&cursor[d], 1);
        csr_src[pos]  = s;
        csr_coef[pos] = norm_out[s];
    }
}

// ---- x projections + W^T cast: grid (4, 8); g==3 does wt transpose ------
__global__ __launch_bounds__(256) void xproj_k(const float* __restrict__ x,
                                               const float* __restrict__ w_r, const float* __restrict__ b_r,
                                               const float* __restrict__ w_z, const float* __restrict__ b_z,
                                               const float* __restrict__ w_h, const float* __restrict__ b_h,
                                               const float* __restrict__ gcn_w, ushort_* __restrict__ wt,
                                               float* __restrict__ xr, float* __restrict__ xz, float* __restrict__ xh) {
    const int g = blockIdx.x, b = blockIdx.y;
    if (g == 3) {                    // transpose + cast gcn_w (k,n) -> WT (n,k) bf16
        if (b != 0) return;
        const int t = threadIdx.x;
        const int n = t >> 1;
        const int kb = (t & 1) * 64;
        #pragma unroll
        for (int i = 0; i < 8; ++i) {
            int k = kb + i * 8;
            uint4 o;
            o.x = (uint_)f2bf(gcn_w[(k + 0) * H_ + n]) | ((uint_)f2bf(gcn_w[(k + 1) * H_ + n]) << 16);
            o.y = (uint_)f2bf(gcn_w[(k + 2) * H_ + n]) | ((uint_)f2bf(gcn_w[(k + 3) * H_ + n]) << 16);
            o.z = (uint_)f2bf(gcn_w[(k + 4) * H_ + n]) | ((uint_)f2bf(gcn_w[(k + 5) * H_ + n]) << 16);
            o.w = (uint_)f2bf(gcn_w[(k + 6) * H_ + n]) | ((uint_)f2bf(gcn_w[(k + 7) * H_ + n]) << 16);
            *(uint4*)(wt + n * H_ + k) = o;
        }
        return;
    }
    const float* __restrict__ w  = g == 0 ? w_r : (g == 1 ? w_z : w_h);
    const float* __restrict__ bs = g == 0 ? b_r : (g == 1 ? b_z : b_h);
    float* __restrict__ o        = g == 0 ? xr  : (g == 1 ? xz  : xh);
    const int k = threadIdx.x & 127, half = threadIdx.x >> 7;
    const float* xb = x + b * DIN_;
    float a = 0.f;
    #pragma unroll 8
    for (int d = half * 128; d < half * 128 + 128; ++d)
        a += xb[d] * w[d * H_ + k];
    __shared__ float part[2][128];
    part[half][k] = a;
    __syncthreads();
    if (half == 0) o[b * H_ + k] = a + part[1][k] + bs[k];
}

// ---- GEMM-first: hw = bf16(h_prev @ gcn_w), flattened (B*N, H) ----------
// GraphConv is linear: norm_in*(A(norm_out*h))@W == norm_in*(A(norm_out*(h@W))).
// Block: 64 rows x 128 cols; 4 waves x 16 rows. Swizzled-LDS MFMA scheme.
__global__ __launch_bounds__(256) void gemm_cast_k(const float* __restrict__ h,
                                                   const ushort_* __restrict__ wt,
                                                   ushort_* __restrict__ hw) {
    __shared__ ushort_ WT_s[H_ * H_];   // [n][k] bf16, swizzled: 32 KB
    __shared__ ushort_ A_s[64 * H_];    // [row][k] bf16, swizzled: 16 KB
    const int tid = threadIdx.x;
    const size_t rbase = (size_t)blockIdx.x * 64;   // B_*N_ = 80000 = 1250*64 exact

    // stage W^T: 2048 16B-chunks; swizzle k-ushorts by ((n&7)<<3)
    #pragma unroll
    for (int i = 0; i < 8; ++i) {
        int c = i * 256 + tid;
        int n = c >> 4;
        int kus = (c & 15) * 8;
        uint4 v = ((const uint4*)wt)[c];
        *(uint4*)&WT_s[n * H_ + (kus ^ ((n & 7) << 3))] = v;
    }
    // stage A tile: 64x128 fp32 rows of h_prev -> bf16, swizzled
    #pragma unroll
    for (int i = 0; i < 8; ++i) {
        int f4 = i * 256 + tid;           // float4 id within tile (0..2047)
        int row = f4 >> 5;
        int col4 = (f4 & 31) * 4;
        f32x4 v = *(const f32x4*)&h[(rbase + row) * H_ + col4];
        uint2 p;
        p.x = (uint_)f2bf(v[0]) | ((uint_)f2bf(v[1]) << 16);
        p.y = (uint_)f2bf(v[2]) | ((uint_)f2bf(v[3]) << 16);
        *(uint2*)&A_s[row * H_ + (col4 ^ ((row & 7) << 3))] = p;
    }
    __syncthreads();

    const int l = tid & 63;
    const int w = tid >> 6;
    const int lr = l & 15;
    const int kg = (l >> 4) * 8;
    const int arow = w * 16 + lr;

    f32x4 acc[8];
    #pragma unroll
    for (int nf = 0; nf < 8; ++nf) acc[nf] = (f32x4){0.f, 0.f, 0.f, 0.f};

    #pragma unroll
    for (int kk = 0; kk < 4; ++kk) {
        int kus = kk * 32 + kg;
        short8 av = *(const short8*)&A_s[arow * H_ + (kus ^ ((arow & 7) << 3))];
        #pragma unroll
        for (int nf = 0; nf < 8; ++nf) {
            int nrow = nf * 16 + lr;
            short8 bv = *(const short8*)&WT_s[nrow * H_ + (kus ^ ((nrow & 7) << 3))];
            acc[nf] = __builtin_amdgcn_mfma_f32_16x16x32_bf16(av, bv, acc[nf], 0, 0, 0);
        }
    }

    // epilogue: C/D layout col = lane&15, row = (lane>>4)*4 + r (m89).
    // Scatter acc into this wave's own A_s rows as bf16 (swizzled), then
    // read back row-contiguous for coalesced 64B/lane global stores.
    const int wrow0 = w * 16 + (l >> 4) * 4;
    #pragma unroll
    for (int nf = 0; nf < 8; ++nf) {
        int col = nf * 16 + lr;
        #pragma unroll
        for (int r = 0; r < 4; ++r) {
            int row = wrow0 + r;
            A_s[row * H_ + (col ^ ((row & 7) << 3))] = f2bf(acc[nf][r]);
        }
    }
    __syncthreads();   // cross-lane LDS transpose: make visibility explicit
    {
        int row = w * 16 + (l >> 2);      // 16 rows x 4 col-groups per wave
        int c0 = (l & 3) * 32;            // 32 ushorts = 64B per lane
        int swz = (row & 7) << 3;
        uint4 o0 = *(const uint4*)&A_s[row * H_ + ((c0 +  0) ^ swz)];
        uint4 o1 = *(const uint4*)&A_s[row * H_ + ((c0 +  8) ^ swz)];
        uint4 o2 = *(const uint4*)&A_s[row * H_ + ((c0 + 16) ^ swz)];
        uint4 o3 = *(const uint4*)&A_s[row * H_ + ((c0 + 24) ^ swz)];
        uint4* dst = (uint4*)(hw + (rbase + row) * H_ + c0);
        dst[0] = o0; dst[1] = o1; dst[2] = o2; dst[3] = o3;
    }
}

#define GATHER4(J)                                                         \
    {                                                                      \
        int  q   = (J) + e;                                                \
        bool ok  = q < dc;                                                 \
        int  idx = o + (ok ? q : 0);                                       \
        int   s  = csr_src[idx];                                           \
        float cf = ok ? csr_coef[idx] : 0.f;                               \
        uint4 u  = *(const uint4*)(hb + (size_t)s * H_);                   \
        a[0] += cf * BF_LO(u.x); a[1] += cf * BF_HI(u.x);                  \
        a[2] += cf * BF_LO(u.y); a[3] += cf * BF_HI(u.y);                  \
        a[4] += cf * BF_LO(u.z); a[5] += cf * BF_HI(u.z);                  \
        a[6] += cf * BF_LO(u.w); a[7] += cf * BF_HI(u.w);                  \
    }

// ---- aggregation of hw + fused GRU, one batch per XCD -------------------
// Wave = one (node, batch); batch = blockIdx.x & 7 pins each batch's 2.56MB
// hw slice to one XCD's L2 (round-robin block->XCD dispatch).
// Lanes: e = lane>>4 (4 edge slots) x c = lane&15 (16B col chunk).
// Per iteration: 4 edges, one dwordx4 gather per lane = 1KB/wave/instr.
// Edge-slot partials folded by __shfl_xor(16|32); epilogue 2 cols/lane.
__global__ __launch_bounds__(256) void agg_gru_k(const ushort_* __restrict__ hw, const int* __restrict__ offsets,
                                                 const float* __restrict__ norm_in,
                                                 const int* __restrict__ csr_src, const float* __restrict__ csr_coef,
                                                 const float* __restrict__ gcn_b,
                                                 const float* __restrict__ xr, const float* __restrict__ xz,
                                                 const float* __restrict__ xh,
                                                 const float* __restrict__ h_prev, float* __restrict__ out) {
    const int lane = threadIdx.x & 63;
    const int wave = threadIdx.x >> 6;
    const int b  = blockIdx.x & 7;                  // XCD-pinned batch
    const int ng = blockIdx.x >> 3;                 // node group (0..2499)
    const int n  = ng * 4 + wave;
    const int e  = lane >> 4;                       // edge slot
    const int c  = lane & 15;                       // col chunk (8 bf16)
    const ushort_* __restrict__ hb = hw + (size_t)b * (N_ * H_) + c * 8;
    int o  = offsets[n];
    int dc = offsets[n + 1] - o;
    float a[8];
    #pragma unroll
    for (int k = 0; k < 8; ++k) a[k] = 0.f;
    int j = 0;
    for (; j + 8 <= dc; j += 8) {       // 2 independent 4-edge gathers in flight
        GATHER4(j);
        GATHER4(j + 4);
    }
    for (; j < dc; j += 4) {
        GATHER4(j);
    }
    // fold the 4 edge slots (lane bits 4,5)
    #pragma unroll
    for (int k = 0; k < 8; ++k) {
        a[k] += __shfl_xor(a[k], 16);
        a[k] += __shfl_xor(a[k], 32);
    }
    // each lane finishes 2 columns: col = c*8 + e*2 (static acc selection)
    float a0 = (e == 0) ? a[0] : (e == 1) ? a[2] : (e == 2) ? a[4] : a[6];
    float a1 = (e == 0) ? a[1] : (e == 1) ? a[3] : (e == 2) ? a[5] : a[7];
    float ni = norm_in[n];
    int col = c * 8 + e * 2;
    size_t off = ((size_t)b * N_ + n) * H_ + col;
    float2 hp = *(const float2*)(h_prev + off);
    float2 gb = *(const float2*)(gcn_b + col);
    float2 vr = *(const float2*)(xr + b * H_ + col);
    float2 vz = *(const float2*)(xz + b * H_ + col);
    float2 vh = *(const float2*)(xh + b * H_ + col);
    float2 wv;
    {
        float hc = a0 * ni + gb.x;
        float rr = sigmoidf_(vr.x + hc);
        float zz = sigmoidf_(vz.x + hc);
        float ht = tanh_fast(vh.x + rr * hc);
        wv.x = (1.f - zz) * hp.x + zz * ht;
    }
    {
        float hc = a1 * ni + gb.y;
        float rr = sigmoidf_(vr.y + hc);
        float zz = sigmoidf_(vz.y + hc);
        float ht = tanh_fast(vh.y + rr * hc);
        wv.y = (1.f - zz) * hp.y + zz * ht;
    }
    *(float2*)(out + off) = wv;
}

extern "C" void kernel_launch(void* const* d_in, const int* in_sizes, int n_in,
                              void* d_out, int out_size, void* d_ws, size_t ws_size,
                              hipStream_t stream) {
    (void)in_sizes; (void)n_in; (void)out_size; (void)ws_size;
    const float* x      = (const float*)d_in[0];
    const float* h_prev = (const float*)d_in[1];
    const int*   src    = (const int*)d_in[2];
    const int*   dst    = (const int*)d_in[3];
    const float* w_r    = (const float*)d_in[4];
    const float* b_r    = (const float*)d_in[5];
    const float* w_z    = (const float*)d_in[6];
    const float* b_z    = (const float*)d_in[7];
    const float* w_h    = (const float*)d_in[8];
    const float* b_h    = (const float*)d_in[9];
    const float* gcn_w  = (const float*)d_in[10];
    const float* gcn_b  = (const float*)d_in[11];
    float* out = (float*)d_out;

    ushort_* hw = (ushort_*)d_ws;                        // B*N*H bf16 = 20.48 MB
    int* wsi = (int*)(hw + (size_t)B_ * N_ * H_);
    int* out_deg   = wsi;                       // N
    int* in_deg    = wsi + N_;                  // N
    int* cursor    = wsi + 2 * N_;              // N
    int* offsets   = wsi + 3 * N_;              // N+1
    float* norm_out = (float*)(wsi + 4 * N_ + 1);  // N
    float* norm_in  = norm_out + N_;               // N
    int*   csr_src  = (int*)(norm_in + N_);        // E
    float* csr_coef = (float*)(csr_src + E_);      // E
    float* xr = csr_coef + E_;                     // B*H
    float* xz = xr + B_ * H_;
    float* xh = xz + B_ * H_;
    ushort_* wt = (ushort_*)(xh + B_ * H_);        // H*H bf16 = 32 KB

    hipMemsetAsync(out_deg, 0, 3 * N_ * sizeof(int), stream);  // out_deg, in_deg, cursor
    degrees_k<<<(E_ + 255) / 256, 256, 0, stream>>>(src, dst, out_deg, in_deg);
    norms_scan_k<<<1, 1024, 0, stream>>>(out_deg, in_deg, norm_out, norm_in, offsets);
    fill_csr_k<<<(E_ + 255) / 256, 256, 0, stream>>>(src, dst, offsets, cursor, norm_out, csr_src, csr_coef);
    xproj_k<<<dim3(4, B_), 256, 0, stream>>>(x, w_r, b_r, w_z, b_z, w_h, b_h, gcn_w, wt, xr, xz, xh);
    gemm_cast_k<<<(B_ * N_) / 64, 256, 0, stream>>>(h_prev, wt, hw);
    agg_gru_k<<<(N_ / 4) * 8, 256, 0, stream>>>(hw, offsets, norm_in, csr_src, csr_coef,
                                                gcn_b, xr, xz, xh, h_prev, out);
}